// Round 1
// baseline (144.627 us; speedup 1.0000x reference)
//
#include <hip/hip_runtime.h>
#include <hip/hip_bf16.h>

// Problem constants
#define BB 4
#define CC 128
#define NN 4096
#define KK 32
// ws layout (floats)
#define THETA_OFF 0
#define THETA_SZ  (BB*NN*CC)          // 2097152
#define M_OFF     (THETA_SZ)          // 2097152
#define M_SZ      (CC*CC)             // 16384
#define B2_OFF    (M_OFF + M_SZ)
#define PART_OFF  (B2_OFF + 128)
#define PART_SZ   (512*256)
#define STAT_OFF  (PART_OFF + PART_SZ)

__device__ __forceinline__ float dot4(float4 a, float4 b) {
    return a.x*b.x + a.y*b.y + a.z*b.z + a.w*b.w;
}

// ---------------- Kernel W: M = Ww @ Wg ; b2 = Ww @ bg + bw ----------------
__global__ void kW(const float* __restrict__ Ww, const float* __restrict__ Wg,
                   const float* __restrict__ bg, const float* __restrict__ bw,
                   float* __restrict__ M, float* __restrict__ b2) {
    int t = threadIdx.x;
    if (blockIdx.x < 64) {
        int e = blockIdx.x * 2 + (t >> 7);
        int c = t & 127;
        float acc = 0.f;
#pragma unroll 8
        for (int d = 0; d < 128; ++d)
            acc += Ww[e*128 + d] * Wg[d*128 + c];
        M[e*128 + c] = acc;
    } else if (t < 128) {
        float acc = bw[t];
        for (int d = 0; d < 128; ++d)
            acc += Ww[t*128 + d] * bg[d];
        b2[t] = acc;
    }
}

// ---------------- Kernel T: theta_all = xr @ Wt^T + bt ----------------
// xr[b,n,c] = x_flat[(b*N+n)*C + c] (reshape view). 32 rows per block.
__global__ __launch_bounds__(256) void kTheta(const float* __restrict__ x,
                                              const float* __restrict__ Wt,
                                              const float* __restrict__ bt,
                                              float* __restrict__ theta) {
    __shared__ float xr[32][132];
    __shared__ float wt[128][36];
    int t = threadIdx.x;
    long base = (long)blockIdx.x * (32 * 128);
    // stage 32 contiguous rows (16 KB)
#pragma unroll
    for (int r = 0; r < 4; ++r) {
        int f = (t + 256*r) * 4;
        int dn = f >> 7, c = f & 127;
        *(float4*)&xr[dn][c] = *(const float4*)(x + base + f);
    }
    float acc[4][4] = {};
    int e0 = t & 31, dn0 = (t >> 5) * 4;
    for (int cb = 0; cb < 4; ++cb) {
        __syncthreads();
#pragma unroll
        for (int r = 0; r < 4; ++r) {
            int f = (t + 256*r) * 4;
            int d = f >> 5, cc = f & 31;
            *(float4*)&wt[d][cc] = *(const float4*)(Wt + d*128 + cb*32 + cc);
        }
        __syncthreads();
#pragma unroll
        for (int q = 0; q < 8; ++q) {
            float4 a4[4], m4[4];
#pragma unroll
            for (int j = 0; j < 4; ++j) a4[j] = *(const float4*)&xr[dn0+j][cb*32 + q*4];
#pragma unroll
            for (int i = 0; i < 4; ++i) m4[i] = *(const float4*)&wt[e0 + 32*i][q*4];
#pragma unroll
            for (int i = 0; i < 4; ++i)
#pragma unroll
                for (int j = 0; j < 4; ++j)
                    acc[i][j] += dot4(a4[j], m4[i]);
        }
    }
    __syncthreads();
    // bounce through LDS for coalesced store
#pragma unroll
    for (int i = 0; i < 4; ++i) {
        float b = bt[e0 + 32*i];
#pragma unroll
        for (int j = 0; j < 4; ++j)
            xr[dn0 + j][e0 + 32*i] = acc[i][j] + b;
    }
    __syncthreads();
#pragma unroll
    for (int r = 0; r < 4; ++r) {
        int f = (t + 256*r) * 4;
        int dn = f >> 7, c = f & 127;
        *(float4*)(theta + base + f) = *(const float4*)&xr[dn][c];
    }
}

// ---------------- Main fused kernel ----------------
// Per block: 32 consecutive n of one batch.
// A: logits[n,k] = theta[n]·theta_all[idx[n,k]]; softmax -> coef
// B: agg[n,c] = sum_k coef[n,k]*feature[b,c,n,k]   (coalesced: lanes span n,k)
// C: y[e,n] = sum_c M[e,c]*agg[n,c] + b2[e]; write y + BN partial sums
struct UA { float tc[32][132]; float logits[32][33]; };
struct UC { float mc[128][36]; };
union UU { UA a; UC c; };

__global__ __launch_bounds__(256) void kMain(const int* __restrict__ gi,
                                             const float* __restrict__ feat,
                                             const float* __restrict__ theta,
                                             const float* __restrict__ Mmat,
                                             const float* __restrict__ b2v,
                                             float* __restrict__ y,
                                             float* __restrict__ partial) {
    __shared__ UU u;
    __shared__ float coef[32][36];
    __shared__ float agg[32][132];
    __shared__ float pw[4][128];
    __shared__ float qw[4][128];
    int t = threadIdx.x;
    int b = blockIdx.x >> 7;
    int n0 = (blockIdx.x & 127) * 32;
    long trow0 = (long)blockIdx.x * 32;   // = b*N + n0

    // ---- stage theta rows of this tile (contiguous 16 KB) ----
#pragma unroll
    for (int r = 0; r < 4; ++r) {
        int f = (t + 256*r) * 4;
        int dn = f >> 7, c = f & 127;
        *(float4*)&u.a.tc[dn][c] = *(const float4*)(theta + trow0*128 + f);
    }
    __syncthreads();

    // ---- phase A: logits via gather of theta_all ----
    {
        int k = t >> 3, l8 = t & 7;
        const float* tbat = theta + (long)b * NN * CC;
        for (int dn = 0; dn < 32; ++dn) {
            int idx = gi[(trow0 + dn) * KK + k];
            const float* row = tbat + (long)idx * CC;
            float p = 0.f;
#pragma unroll
            for (int j = 0; j < 4; ++j) {
                int c = j*32 + l8*4;
                float4 g = *(const float4*)(row + c);
                float4 tc = *(const float4*)&u.a.tc[dn][c];
                p += dot4(g, tc);
            }
            p += __shfl_xor(p, 1);
            p += __shfl_xor(p, 2);
            p += __shfl_xor(p, 4);
            if (l8 == 0) u.a.logits[dn][k] = p;
        }
    }
    __syncthreads();

    // ---- softmax over k (8 lanes per row) ----
    {
        int row = t >> 3, l8 = t & 7;
        float l[4];
#pragma unroll
        for (int j = 0; j < 4; ++j) l[j] = u.a.logits[row][l8 + 8*j];
        float m = fmaxf(fmaxf(l[0], l[1]), fmaxf(l[2], l[3]));
        m = fmaxf(m, __shfl_xor(m, 1));
        m = fmaxf(m, __shfl_xor(m, 2));
        m = fmaxf(m, __shfl_xor(m, 4));
        float e[4]; float s = 0.f;
#pragma unroll
        for (int j = 0; j < 4; ++j) { e[j] = __expf(l[j] - m); s += e[j]; }
        s += __shfl_xor(s, 1);
        s += __shfl_xor(s, 2);
        s += __shfl_xor(s, 4);
        float inv = 1.0f / s;
#pragma unroll
        for (int j = 0; j < 4; ++j) coef[row][l8 + 8*j] = e[j] * inv;
    }
    __syncthreads();

    // ---- phase B: agg[n][c] = sum_k coef*feature ----
    {
        int dn = t >> 3, k4 = (t & 7) * 4;
        float4 cf = *(const float4*)&coef[dn][k4];
        const float* fb = feat + (size_t)b * (CC*NN*KK) + (size_t)(n0 + dn) * KK + k4;
        for (int c = 0; c < 128; c += 4) {
            float4 f0 = *(const float4*)(fb + (size_t)(c+0) * (NN*KK));
            float4 f1 = *(const float4*)(fb + (size_t)(c+1) * (NN*KK));
            float4 f2 = *(const float4*)(fb + (size_t)(c+2) * (NN*KK));
            float4 f3 = *(const float4*)(fb + (size_t)(c+3) * (NN*KK));
            float v0 = dot4(f0, cf);
            float v1 = dot4(f1, cf);
            float v2 = dot4(f2, cf);
            float v3 = dot4(f3, cf);
            v0 += __shfl_xor(v0,1); v0 += __shfl_xor(v0,2); v0 += __shfl_xor(v0,4);
            v1 += __shfl_xor(v1,1); v1 += __shfl_xor(v1,2); v1 += __shfl_xor(v1,4);
            v2 += __shfl_xor(v2,1); v2 += __shfl_xor(v2,2); v2 += __shfl_xor(v2,4);
            v3 += __shfl_xor(v3,1); v3 += __shfl_xor(v3,2); v3 += __shfl_xor(v3,4);
            if ((t & 7) == 0) {
                agg[dn][c]   = v0;
                agg[dn][c+1] = v1;
                agg[dn][c+2] = v2;
                agg[dn][c+3] = v3;
            }
        }
    }
    __syncthreads();

    // ---- phase C: y = agg @ M^T + b2 ----
    float acc[4][4] = {};
    int e0 = t & 31, dn0 = (t >> 5) * 4;
    for (int cb = 0; cb < 4; ++cb) {
#pragma unroll
        for (int r = 0; r < 4; ++r) {
            int f = (t + 256*r) * 4;
            int e = f >> 5, cc = f & 31;
            *(float4*)&u.c.mc[e][cc] = *(const float4*)(Mmat + e*128 + cb*32 + cc);
        }
        __syncthreads();
#pragma unroll
        for (int q = 0; q < 8; ++q) {
            float4 a4[4], m4[4];
#pragma unroll
            for (int j = 0; j < 4; ++j) a4[j] = *(const float4*)&agg[dn0+j][cb*32 + q*4];
#pragma unroll
            for (int i = 0; i < 4; ++i) m4[i] = *(const float4*)&u.c.mc[e0 + 32*i][q*4];
#pragma unroll
            for (int i = 0; i < 4; ++i)
#pragma unroll
                for (int j = 0; j < 4; ++j)
                    acc[i][j] += dot4(a4[j], m4[i]);
        }
        __syncthreads();
    }

    // ---- epilogue: write y, deterministic BN partials ----
    int w = t >> 6;
#pragma unroll
    for (int i = 0; i < 4; ++i) {
        int e = e0 + 32*i;
        float bb = b2v[e];
        float4 yv;
        yv.x = acc[i][0] + bb;
        yv.y = acc[i][1] + bb;
        yv.z = acc[i][2] + bb;
        yv.w = acc[i][3] + bb;
        *(float4*)(y + ((long)(b*CC + e)) * NN + n0 + dn0) = yv;
        float s = yv.x + yv.y + yv.z + yv.w;
        float qq = yv.x*yv.x + yv.y*yv.y + yv.z*yv.z + yv.w*yv.w;
        s  += __shfl_xor(s, 32);
        qq += __shfl_xor(qq, 32);
        if (!(t & 32)) { pw[w][e] = s; qw[w][e] = qq; }
    }
    __syncthreads();
    if (t < 128) {
        partial[(long)blockIdx.x * 256 + t]       = pw[0][t] + pw[1][t] + pw[2][t] + pw[3][t];
        partial[(long)blockIdx.x * 256 + 128 + t] = qw[0][t] + qw[1][t] + qw[2][t] + qw[3][t];
    }
}

// ---------------- Kernel R: reduce partials -> scale/shift per channel ----------------
__global__ void kR(const float* __restrict__ partial,
                   const float* __restrict__ gamma, const float* __restrict__ beta,
                   float* __restrict__ stats) {
    __shared__ float buf[256];
    int t = threadIdx.x;
    float acc = 0.f;
#pragma unroll 8
    for (int pb = 0; pb < 512; ++pb)
        acc += partial[pb*256 + t];
    buf[t] = acc;
    __syncthreads();
    if (t < 128) {
        float S = buf[t], Q = buf[t + 128];
        const float invN = 1.0f / (BB * NN);
        float mean = S * invN;
        float var  = Q * invN - mean * mean;
        float sc = rsqrtf(var + 1e-5f) * gamma[t];
        stats[t]       = sc;
        stats[128 + t] = beta[t] - mean * sc;
    }
}

// ---------------- Kernel Z: in-place normalize ----------------
__global__ void kZ(float* __restrict__ y, const float* __restrict__ stats) {
    int idx = blockIdx.x * 256 + threadIdx.x;   // float4 index
#pragma unroll
    for (int r = 0; r < 2; ++r) {
        int i = idx + r * 262144;
        int e = (i >> 10) & 127;
        float sc = stats[e], sh = stats[128 + e];
        float4 v = ((float4*)y)[i];
        v.x = v.x * sc + sh;
        v.y = v.y * sc + sh;
        v.z = v.z * sc + sh;
        v.w = v.w * sc + sh;
        ((float4*)y)[i] = v;
    }
}

extern "C" void kernel_launch(void* const* d_in, const int* in_sizes, int n_in,
                              void* d_out, int out_size, void* d_ws, size_t ws_size,
                              hipStream_t stream) {
    const int*   gi    = (const int*)d_in[0];
    const float* x     = (const float*)d_in[1];
    const float* feat  = (const float*)d_in[2];
    const float* Wt    = (const float*)d_in[3];
    const float* bt    = (const float*)d_in[4];
    const float* Wg    = (const float*)d_in[5];
    const float* bg    = (const float*)d_in[6];
    const float* Ww    = (const float*)d_in[7];
    const float* bw    = (const float*)d_in[8];
    const float* gamma = (const float*)d_in[9];
    const float* beta  = (const float*)d_in[10];

    float* y  = (float*)d_out;
    float* ws = (float*)d_ws;
    float* theta   = ws + THETA_OFF;
    float* Mmat    = ws + M_OFF;
    float* b2      = ws + B2_OFF;
    float* partial = ws + PART_OFF;
    float* stats   = ws + STAT_OFF;

    kW<<<65, 256, 0, stream>>>(Ww, Wg, bg, bw, Mmat, b2);
    kTheta<<<512, 256, 0, stream>>>(x, Wt, bt, theta);
    kMain<<<512, 256, 0, stream>>>(gi, feat, theta, Mmat, b2, y, partial);
    kR<<<1, 256, 0, stream>>>(partial, gamma, beta, stats);
    kZ<<<1024, 256, 0, stream>>>(y, stats);
}

// Round 2
// 133.726 us; speedup vs baseline: 1.0815x; 1.0815x over previous
//
#include <hip/hip_runtime.h>
#include <hip/hip_bf16.h>

// Problem constants
#define BB 4
#define CC 128
#define NN 4096
#define KK 32
// ws layout (floats). agg aliases theta (theta dead after kA).
#define THETA_OFF 0
#define THETA_SZ  (BB*NN*CC)          // 2097152 floats (8 MB)
#define AGG_OFF   THETA_OFF           // alias: theta consumed by kA before kB writes agg
#define M_OFF     (THETA_SZ)
#define M_SZ      (CC*CC)
#define B2_OFF    (M_OFF + M_SZ)
#define COEF_OFF  (B2_OFF + 128)
#define COEF_SZ   (BB*NN*KK)          // 524288 floats (2 MB)
#define PART_OFF  (COEF_OFF + COEF_SZ)
#define PART_SZ   (512*256)
#define STAT_OFF  (PART_OFF + PART_SZ)

__device__ __forceinline__ float dot4(float4 a, float4 b) {
    return a.x*b.x + a.y*b.y + a.z*b.z + a.w*b.w;
}

// ---------------- Kernel W: M = Ww @ Wg ; b2 = Ww @ bg + bw ----------------
__global__ void kW(const float* __restrict__ Ww, const float* __restrict__ Wg,
                   const float* __restrict__ bg, const float* __restrict__ bw,
                   float* __restrict__ M, float* __restrict__ b2) {
    int t = threadIdx.x;
    if (blockIdx.x < 64) {
        int e = blockIdx.x * 2 + (t >> 7);
        int c = t & 127;
        float acc = 0.f;
#pragma unroll 8
        for (int d = 0; d < 128; ++d)
            acc += Ww[e*128 + d] * Wg[d*128 + c];
        M[e*128 + c] = acc;
    } else if (t < 128) {
        float acc = bw[t];
        for (int d = 0; d < 128; ++d)
            acc += Ww[t*128 + d] * bg[d];
        b2[t] = acc;
    }
}

// ---------------- Kernel T: theta_all = xr @ Wt^T + bt ----------------
__global__ __launch_bounds__(256) void kTheta(const float* __restrict__ x,
                                              const float* __restrict__ Wt,
                                              const float* __restrict__ bt,
                                              float* __restrict__ theta) {
    __shared__ float xr[32][132];
    __shared__ float wt[128][36];
    int t = threadIdx.x;
    long base = (long)blockIdx.x * (32 * 128);
#pragma unroll
    for (int r = 0; r < 4; ++r) {
        int f = (t + 256*r) * 4;
        int dn = f >> 7, c = f & 127;
        *(float4*)&xr[dn][c] = *(const float4*)(x + base + f);
    }
    float acc[4][4] = {};
    int e0 = t & 31, dn0 = (t >> 5) * 4;
    for (int cb = 0; cb < 4; ++cb) {
        __syncthreads();
#pragma unroll
        for (int r = 0; r < 4; ++r) {
            int f = (t + 256*r) * 4;
            int d = f >> 5, cc = f & 31;
            *(float4*)&wt[d][cc] = *(const float4*)(Wt + d*128 + cb*32 + cc);
        }
        __syncthreads();
#pragma unroll
        for (int q = 0; q < 8; ++q) {
            float4 a4[4], m4[4];
#pragma unroll
            for (int j = 0; j < 4; ++j) a4[j] = *(const float4*)&xr[dn0+j][cb*32 + q*4];
#pragma unroll
            for (int i = 0; i < 4; ++i) m4[i] = *(const float4*)&wt[e0 + 32*i][q*4];
#pragma unroll
            for (int i = 0; i < 4; ++i)
#pragma unroll
                for (int j = 0; j < 4; ++j)
                    acc[i][j] += dot4(a4[j], m4[i]);
        }
    }
    __syncthreads();
#pragma unroll
    for (int i = 0; i < 4; ++i) {
        float b = bt[e0 + 32*i];
#pragma unroll
        for (int j = 0; j < 4; ++j)
            xr[dn0 + j][e0 + 32*i] = acc[i][j] + b;
    }
    __syncthreads();
#pragma unroll
    for (int r = 0; r < 4; ++r) {
        int f = (t + 256*r) * 4;
        int dn = f >> 7, c = f & 127;
        *(float4*)(theta + base + f) = *(const float4*)&xr[dn][c];
    }
}

// ---------------- Kernel A: coef = softmax_k(theta[n] . theta[idx[n,k]]) ----------------
// 16 rows per block, 1024 blocks.
__global__ __launch_bounds__(256) void kA(const int* __restrict__ gi,
                                          const float* __restrict__ theta,
                                          float* __restrict__ coefG) {
    __shared__ float tc[16][132];
    __shared__ float logits[16][33];
    int t = threadIdx.x;
    long trow0 = (long)blockIdx.x * 16;         // = b*N + n0
    int b = blockIdx.x >> 8;                    // 256 blocks per batch
    // stage 16 theta rows (8 KB contiguous)
#pragma unroll
    for (int r = 0; r < 2; ++r) {
        int f = (t + 256*r) * 4;
        int dn = f >> 7, c = f & 127;
        *(float4*)&tc[dn][c] = *(const float4*)(theta + trow0*128 + f);
    }
    __syncthreads();
    // gather + logits
    {
        int k = t >> 3, l8 = t & 7;
        const float* tbat = theta + (long)b * NN * CC;
        for (int dn = 0; dn < 16; ++dn) {
            int idx = gi[(trow0 + dn) * KK + k];
            const float* row = tbat + (long)idx * CC;
            float p = 0.f;
#pragma unroll
            for (int j = 0; j < 4; ++j) {
                int c = j*32 + l8*4;
                float4 g = *(const float4*)(row + c);
                float4 tcv = *(const float4*)&tc[dn][c];
                p += dot4(g, tcv);
            }
            p += __shfl_xor(p, 1);
            p += __shfl_xor(p, 2);
            p += __shfl_xor(p, 4);
            if (l8 == 0) logits[dn][k] = p;
        }
    }
    __syncthreads();
    // softmax over k (first 128 threads: 8 lanes per row)
    if (t < 128) {
        int row = t >> 3, l8 = t & 7;
        float l[4];
#pragma unroll
        for (int j = 0; j < 4; ++j) l[j] = logits[row][l8 + 8*j];
        float m = fmaxf(fmaxf(l[0], l[1]), fmaxf(l[2], l[3]));
        m = fmaxf(m, __shfl_xor(m, 1));
        m = fmaxf(m, __shfl_xor(m, 2));
        m = fmaxf(m, __shfl_xor(m, 4));
        float e[4]; float s = 0.f;
#pragma unroll
        for (int j = 0; j < 4; ++j) { e[j] = __expf(l[j] - m); s += e[j]; }
        s += __shfl_xor(s, 1);
        s += __shfl_xor(s, 2);
        s += __shfl_xor(s, 4);
        float inv = 1.0f / s;
#pragma unroll
        for (int j = 0; j < 4; ++j)
            coefG[(trow0 + row) * KK + l8 + 8*j] = e[j] * inv;
    }
}

// ---------------- Kernel B: agg[n][c] = sum_k coef[n][k]*feature[b][c][n][k] ----------------
// One block = 32 n x 32 c chunk. Grid = 512 tiles * 4 c-chunks = 2048 blocks.
__global__ __launch_bounds__(256, 6) void kB(const float* __restrict__ coefG,
                                             const float* __restrict__ feat,
                                             float* __restrict__ aggG) {
    __shared__ float ag[32][36];
    int t = threadIdx.x;
    int cc4 = blockIdx.x & 3;
    int tile = blockIdx.x >> 2;          // b*128 + nt
    int b = tile >> 7;
    int n0 = (tile & 127) * 32;
    int dn = t >> 3, k4i = (t & 7) * 4;
    long nrow = (long)b * NN + n0 + dn;
    float4 cf = *(const float4*)(coefG + nrow * KK + k4i);
    const size_t S = (size_t)NN * KK;
    const float* fb = feat + ((size_t)b * CC + cc4 * 32) * S + (size_t)(n0 + dn) * KK + k4i;
    for (int c0 = 0; c0 < 32; c0 += 8) {
        float4 f[8];
#pragma unroll
        for (int i = 0; i < 8; ++i)
            f[i] = *(const float4*)(fb + (size_t)(c0 + i) * S);
        float v[8];
#pragma unroll
        for (int i = 0; i < 8; ++i) {
            v[i] = dot4(f[i], cf);
            v[i] += __shfl_xor(v[i], 1);
            v[i] += __shfl_xor(v[i], 2);
            v[i] += __shfl_xor(v[i], 4);
        }
        if ((t & 7) == 0) {
#pragma unroll
            for (int i = 0; i < 8; ++i) ag[dn][c0 + i] = v[i];
        }
    }
    __syncthreads();
    int row = t >> 3, col4 = (t & 7) * 4;
    *(float4*)(aggG + ((size_t)b * NN + n0 + row) * CC + cc4 * 32 + col4) =
        *(const float4*)&ag[row][col4];
}

// ---------------- Kernel C: y = agg @ M^T + b2; BN partials ----------------
__global__ __launch_bounds__(256) void kC(const float* __restrict__ aggG,
                                          const float* __restrict__ Mmat,
                                          const float* __restrict__ b2v,
                                          float* __restrict__ y,
                                          float* __restrict__ partial) {
    __shared__ float agg[32][132];
    __shared__ float mc[128][36];
    __shared__ float pw[4][128];
    __shared__ float qw[4][128];
    int t = threadIdx.x;
    int b = blockIdx.x >> 7;
    int n0 = (blockIdx.x & 127) * 32;
    long base = (long)blockIdx.x * (32 * 128);
    // stage agg tile (16 KB contiguous)
#pragma unroll
    for (int r = 0; r < 4; ++r) {
        int f = (t + 256*r) * 4;
        int dn = f >> 7, c = f & 127;
        *(float4*)&agg[dn][c] = *(const float4*)(aggG + base + f);
    }
    float acc[4][4] = {};
    int e0 = t & 31, dn0 = (t >> 5) * 4;
    for (int cb = 0; cb < 4; ++cb) {
        __syncthreads();
#pragma unroll
        for (int r = 0; r < 4; ++r) {
            int f = (t + 256*r) * 4;
            int e = f >> 5, cc = f & 31;
            *(float4*)&mc[e][cc] = *(const float4*)(Mmat + e*128 + cb*32 + cc);
        }
        __syncthreads();
#pragma unroll
        for (int q = 0; q < 8; ++q) {
            float4 a4[4], m4[4];
#pragma unroll
            for (int j = 0; j < 4; ++j) a4[j] = *(const float4*)&agg[dn0+j][cb*32 + q*4];
#pragma unroll
            for (int i = 0; i < 4; ++i) m4[i] = *(const float4*)&mc[e0 + 32*i][q*4];
#pragma unroll
            for (int i = 0; i < 4; ++i)
#pragma unroll
                for (int j = 0; j < 4; ++j)
                    acc[i][j] += dot4(a4[j], m4[i]);
        }
    }
    __syncthreads();
    int w = t >> 6;
#pragma unroll
    for (int i = 0; i < 4; ++i) {
        int e = e0 + 32*i;
        float bb = b2v[e];
        float4 yv;
        yv.x = acc[i][0] + bb;
        yv.y = acc[i][1] + bb;
        yv.z = acc[i][2] + bb;
        yv.w = acc[i][3] + bb;
        *(float4*)(y + ((long)(b*CC + e)) * NN + n0 + dn0) = yv;
        float s = yv.x + yv.y + yv.z + yv.w;
        float qq = yv.x*yv.x + yv.y*yv.y + yv.z*yv.z + yv.w*yv.w;
        s  += __shfl_xor(s, 32);
        qq += __shfl_xor(qq, 32);
        if (!(t & 32)) { pw[w][e] = s; qw[w][e] = qq; }
    }
    __syncthreads();
    if (t < 128) {
        partial[(long)blockIdx.x * 256 + t]       = pw[0][t] + pw[1][t] + pw[2][t] + pw[3][t];
        partial[(long)blockIdx.x * 256 + 128 + t] = qw[0][t] + qw[1][t] + qw[2][t] + qw[3][t];
    }
}

// ---------------- Kernel R: reduce partials -> scale/shift per channel ----------------
__global__ void kR(const float* __restrict__ partial,
                   const float* __restrict__ gamma, const float* __restrict__ beta,
                   float* __restrict__ stats) {
    __shared__ float buf[256];
    int t = threadIdx.x;
    float acc = 0.f;
#pragma unroll 8
    for (int pb = 0; pb < 512; ++pb)
        acc += partial[pb*256 + t];
    buf[t] = acc;
    __syncthreads();
    if (t < 128) {
        float S = buf[t], Q = buf[t + 128];
        const float invN = 1.0f / (BB * NN);
        float mean = S * invN;
        float var  = Q * invN - mean * mean;
        float sc = rsqrtf(var + 1e-5f) * gamma[t];
        stats[t]       = sc;
        stats[128 + t] = beta[t] - mean * sc;
    }
}

// ---------------- Kernel Z: in-place normalize ----------------
__global__ void kZ(float* __restrict__ y, const float* __restrict__ stats) {
    int idx = blockIdx.x * 256 + threadIdx.x;   // float4 index
#pragma unroll
    for (int r = 0; r < 2; ++r) {
        int i = idx + r * 262144;
        int e = (i >> 10) & 127;
        float sc = stats[e], sh = stats[128 + e];
        float4 v = ((float4*)y)[i];
        v.x = v.x * sc + sh;
        v.y = v.y * sc + sh;
        v.z = v.z * sc + sh;
        v.w = v.w * sc + sh;
        ((float4*)y)[i] = v;
    }
}

extern "C" void kernel_launch(void* const* d_in, const int* in_sizes, int n_in,
                              void* d_out, int out_size, void* d_ws, size_t ws_size,
                              hipStream_t stream) {
    const int*   gi    = (const int*)d_in[0];
    const float* x     = (const float*)d_in[1];
    const float* feat  = (const float*)d_in[2];
    const float* Wt    = (const float*)d_in[3];
    const float* bt    = (const float*)d_in[4];
    const float* Wg    = (const float*)d_in[5];
    const float* bg    = (const float*)d_in[6];
    const float* Ww    = (const float*)d_in[7];
    const float* bw    = (const float*)d_in[8];
    const float* gamma = (const float*)d_in[9];
    const float* beta  = (const float*)d_in[10];

    float* y  = (float*)d_out;
    float* ws = (float*)d_ws;
    float* theta   = ws + THETA_OFF;
    float* aggG    = ws + AGG_OFF;    // aliases theta (safe: theta dead after kA)
    float* Mmat    = ws + M_OFF;
    float* b2      = ws + B2_OFF;
    float* coefG   = ws + COEF_OFF;
    float* partial = ws + PART_OFF;
    float* stats   = ws + STAT_OFF;

    kW<<<65, 256, 0, stream>>>(Ww, Wg, bg, bw, Mmat, b2);
    kTheta<<<512, 256, 0, stream>>>(x, Wt, bt, theta);
    kA<<<1024, 256, 0, stream>>>(gi, theta, coefG);
    kB<<<2048, 256, 0, stream>>>(coefG, feat, aggG);
    kC<<<512, 256, 0, stream>>>(aggG, Mmat, b2, y, partial);
    kR<<<1, 256, 0, stream>>>(partial, gamma, beta, stats);
    kZ<<<1024, 256, 0, stream>>>(y, stats);
}